// Round 6
// baseline (1061.852 us; speedup 1.0000x reference)
//
#include <hip/hip_runtime.h>

// HGTPolicy: 2-layer heterogeneous graph transformer + pooling + value/policy heads.
// All tensors float32. Round-6: parallel scan, wide pool, batched kqv/out/policy.

// ---------------- zero fill (u32) ----------------
__global__ void k_zero(unsigned int* p, int n) {
    int i = blockIdx.x * 256 + threadIdx.x;
    int stride = gridDim.x * 256;
    for (; i < n; i += stride) p[i] = 0u;
}

// ---------------- edge flattening + dst histogram ----------------
__global__ void k_flat(const int* epair, int E, int soff, int doff, int et, int eoff,
                       int* gdst, int* pack, int* cnt) {
    int i = blockIdx.x * 256 + threadIdx.x;
    if (i >= E) return;
    int gs = epair[i] + soff;
    int gd = epair[E + i] + doff;
    gdst[eoff + i] = gd;
    pack[eoff + i] = gs | (et << 24);
    atomicAdd(&cnt[gd], 1);
}

// ---------------- single-block parallel exclusive scan ----------------
__global__ void k_scan(const int* cnt, int* rowptr, int* cursor, int Ntot, int Etot) {
    __shared__ int s[1024];
    int t = threadIdx.x;                       // 1024 threads
    int chunk = (Ntot + 1023) >> 10;
    int lo = t * chunk;
    int hi = lo + chunk; if (hi > Ntot) hi = Ntot;
    int sum = 0;
    for (int i = lo; i < hi; i++) sum += cnt[i];
    s[t] = sum;
    __syncthreads();
    for (int off = 1; off < 1024; off <<= 1) {   // Hillis-Steele inclusive
        int add = (t >= off) ? s[t - off] : 0;
        __syncthreads();
        s[t] += add;
        __syncthreads();
    }
    int run = (t > 0) ? s[t - 1] : 0;            // exclusive prefix of this chunk
    for (int i = lo; i < hi; i++) {
        rowptr[i] = run;
        cursor[i] = run;
        run += cnt[i];
    }
    if (t == 0) rowptr[Ntot] = Etot;
}

__global__ void k_scatter(const int* gdst, const int* pack, int* cursor, int* csr, int Etot) {
    int i = blockIdx.x * 256 + threadIdx.x;
    if (i >= Etot) return;
    int d = gdst[i];
    int pos = atomicAdd(&cursor[d], 1);
    csr[pos] = pack[i];
}

// ---------------- embedding + moment accumulation (grid-stride) ----------------
__global__ void k_embed(const float* x, const float* W, const float* b,
                        int F, int N, float* X, float* acc) {
    int j = threadIdx.x;   // 64
    float wj[8];
    for (int k = 0; k < F; k++) wj[k] = W[k * 64 + j];
    float bj = b[j];
    float s1 = 0.0f, s2 = 0.0f;
    for (int n = blockIdx.x; n < N; n += gridDim.x) {
        const float* xr = x + (size_t)n * F;
        float a = bj;
        for (int k = 0; k < F; k++) a += xr[k] * wj[k];
        X[(size_t)n * 64 + j] = a;
        s1 += a;
        s2 += a * a;
    }
    __shared__ float r1[64];
    __shared__ float r2[64];
    r1[j] = s1; r2[j] = s2;
    __syncthreads();
    for (int o = 32; o > 0; o >>= 1) {
        if (j < o) { r1[j] += r1[j + o]; r2[j] += r2[j + o]; }
        __syncthreads();
    }
    if (j == 0) { atomicAdd(&acc[0], r1[0]); atomicAdd(&acc[1], r2[0]); }
}

// ---------------- graph-norm over all N*64 elements of one node type ----------
__global__ void k_gnorm(float* X, const float* acc, const float* gamma,
                        const float* beta, int N) {
    int i = blockIdx.x * 256 + threadIdx.x;
    int tot = N * 64;
    if (i >= tot) return;
    float inv = 1.0f / (float)tot;
    float mu  = acc[0] * inv;
    float var = acc[1] * inv - mu * mu;
    float sd  = sqrtf(fmaxf(var, 0.0f));
    float sc  = 1.0f / (sd + 1e-5f);
    int j = i & 63;
    X[i] = (X[i] - mu) * sc * gamma[j] + beta[j];
}

// ---------------- KQV projection: one wave per node, 4 nodes/block ----------------
__global__ void k_kqv(const float* X, const float* Wkqv, const float* bkqv,
                      float* KQV, int N0, int N1, int l, int Ntot) {
    __shared__ float xs[4][64];
    int tid = threadIdx.x;           // 256
    int w = tid >> 6, j = tid & 63;
    int n = blockIdx.x * 4 + w;
    int valid = (n < Ntot);
    if (valid) xs[w][j] = X[(size_t)n * 64 + j];
    __syncthreads();
    if (!valid) return;
    int t = (n < N0) ? 0 : ((n < N0 + N1) ? 1 : 2);
    const float* W = Wkqv + (size_t)(l * 3 + t) * 64 * 192;
    const float* b = bkqv + (size_t)(l * 3 + t) * 192;
    float a0 = b[j], a1 = b[64 + j], a2 = b[128 + j];
    const float* xw = xs[w];
    for (int k = 0; k < 64; k++) {
        float xk = xw[k];
        const float* Wk = W + k * 192;
        a0 += xk * Wk[j];
        a1 += xk * Wk[64 + j];
        a2 += xk * Wk[128 + j];
    }
    float* dst = KQV + (size_t)n * 192;
    dst[j] = a0; dst[64 + j] = a1; dst[128 + j] = a2;
}

// ---------------- fused attention + aggregation: one wave per dst node ----------
__global__ void k_attnagg(const float* KQV, const int* csr, const int* rowptr,
                          const float* krel_l, const float* vrel_l, const float* prel_l,
                          float* agg, int Ntot) {
    // LDS rel tables, stride 72 per (et,h) to break 8-way bank aliasing
    __shared__ float KRs[8 * 8 * 72];
    __shared__ float VRs[8 * 8 * 72];
    __shared__ float PRs[64];
    int tid = threadIdx.x;   // 256
    for (int i = tid; i < 4096; i += 256) {
        int eth = i >> 6, rest = i & 63;
        KRs[eth * 72 + rest] = krel_l[i];
        VRs[eth * 72 + rest] = vrel_l[i];
    }
    if (tid < 64) PRs[tid] = prel_l[tid];
    __syncthreads();

    int j = tid & 63, h = j >> 3, ee = j & 7;
    int wave  = blockIdx.x * 4 + (tid >> 6);
    int nwave = gridDim.x * 4;
    for (int n = wave; n < Ntot; n += nwave) {
        float qv = KQV[(size_t)n * 192 + 64 + j];
        float num = 0.0f, den = 0.0f;
        int e0 = rowptr[n], e1 = rowptr[n + 1];
        for (int idx = e0; idx < e1; idx++) {
            int pk = csr[idx];
            int sn = pk & 0xFFFFFF;
            int et = ((unsigned int)pk) >> 24;
            const float* kr = KQV + (size_t)sn * 192 + h * 8;
            const float* vr = kr + 128;
            const float* KR = KRs + (et * 8 + h) * 72;
            const float* VR = VRs + (et * 8 + h) * 72;
            float ke = 0.0f, ve = 0.0f;
#pragma unroll
            for (int d = 0; d < 8; d++) {
                float kd = kr[d], vd = vr[d];
                ke += kd * KR[d * 8 + ee];
                ve += vd * VR[d * 8 + ee];
            }
            float t = qv * ke;                  // reduce over ee within head group
            t += __shfl_xor(t, 1);
            t += __shfl_xor(t, 2);
            t += __shfl_xor(t, 4);
            float ex = expf(t * PRs[et * 8 + h] * 0.35355339059327373f);
            num += ex * ve;
            den += ex;
        }
        agg[(size_t)n * 64 + j] = (den > 0.0f) ? (num / den) : 0.0f;
    }
}

// ---------------- output projection + skip gate: one wave/node, 4 nodes/block ----
__global__ void k_out(const float* agg, float* X, const float* Wout,
                      const float* bout, const float* skip, int N0, int N1, int l,
                      int Ntot) {
    __shared__ float ga[4][64];
    int tid = threadIdx.x;           // 256
    int w = tid >> 6, j = tid & 63;
    int n = blockIdx.x * 4 + w;
    int valid = (n < Ntot);
    float xold = 0.0f;
    if (valid) {
        float x = agg[(size_t)n * 64 + j];
        ga[w][j] = 0.5f * x * (1.0f + erff(x * 0.70710678118654752f));  // exact gelu
        xold = X[(size_t)n * 64 + j];
    }
    __syncthreads();
    if (!valid) return;
    int t = (n < N0) ? 0 : ((n < N0 + N1) ? 1 : 2);
    const float* W = Wout + (size_t)(l * 3 + t) * 64 * 64;
    const float* b = bout + (size_t)(l * 3 + t) * 64;
    const float* gw = ga[w];
    float o = b[j];
    for (int k = 0; k < 64; k++) o += gw[k] * W[k * 64 + j];
    float gk = 1.0f / (1.0f + expf(-skip[l * 3 + t]));
    X[(size_t)n * 64 + j] = gk * o + (1.0f - gk) * xold;
}

// ---------------- global mean pooling (wide: 128x3 blocks of 256) ----------------
__global__ void k_pool(const float* X, float* gsum, int N0, int N1, int N2) {
    __shared__ float red[256];
    int t = blockIdx.y;
    int tid = threadIdx.x;
    int j = tid & 63, w = tid >> 6;
    int N   = (t == 0) ? N0 : ((t == 1) ? N1 : N2);
    int off = (t == 0) ? 0  : ((t == 1) ? N0 : N0 + N1);
    const float* base = X + (size_t)off * 64;
    float s = 0.0f;
    for (int r = blockIdx.x * 4 + w; r < N; r += gridDim.x * 4)
        s += base[(size_t)r * 64 + j];
    red[tid] = s;
    __syncthreads();
    if (tid < 64) {
        float tot = red[j] + red[64 + j] + red[128 + j] + red[192 + j];
        atomicAdd(&gsum[t * 64 + j], tot);
    }
}

// ---------------- value head (one block, 192 threads) ----------------
__global__ void k_value(const float* gsum, float* gvec, const float* Wv1,
                        const float* bv1, const float* Wv2, const float* bv2,
                        float* out_val, int N0, int N1, int N2) {
    __shared__ float g[192];
    __shared__ float h1[64];
    int j = threadIdx.x;
    float Nd = (j < 64) ? (float)N0 : ((j < 128) ? (float)N1 : (float)N2);
    float gv = gsum[j] / Nd;
    g[j] = gv;
    gvec[j] = gv;
    __syncthreads();
    if (j < 64) {
        float a = bv1[j];
        for (int k = 0; k < 192; k++) a += g[k] * Wv1[k * 64 + j];
        h1[j] = fmaxf(a, 0.0f);
    }
    __syncthreads();
    if (j == 0) {
        float v = bv2[0];
        for (int k = 0; k < 64; k++) v += h1[k] * Wv2[k];
        out_val[0] = v;
    }
}

// ---------------- policy head: 4 pairs per 256-thread block ----------------
__global__ void HGTPolicy_53051436040798_kernel(
        const float* X, const float* gvec, const int* op_idx, const int* m_idx,
        const float* Wp1, const float* bp1, const float* Wp2, const float* bp2,
        const float* Wp3, const float* bp3, float* out, int N0, int P) {
    __shared__ float z[4][320];
    __shared__ float h1[4][64];
    __shared__ float h2[4][32];
    int tid = threadIdx.x;           // 256
    int pp = tid >> 6, j = tid & 63;
    int p = blockIdx.x * 4 + pp;
    int valid = (p < P);
    if (valid) {
        int on = op_idx[p], mn = m_idx[p];
        z[pp][j]       = X[(size_t)on * 64 + j];
        z[pp][64 + j]  = X[(size_t)(N0 + mn) * 64 + j];
        z[pp][128 + j] = gvec[j];
        z[pp][192 + j] = gvec[64 + j];
        z[pp][256 + j] = gvec[128 + j];
    }
    __syncthreads();
    if (valid) {
        const float* zp = z[pp];
        float a = bp1[j];
        for (int k = 0; k < 320; k++) a += zp[k] * Wp1[k * 64 + j];
        h1[pp][j] = fmaxf(a, 0.0f);
    }
    __syncthreads();
    if (valid && j < 32) {
        const float* hp = h1[pp];
        float a2 = bp2[j];
        for (int k = 0; k < 64; k++) a2 += hp[k] * Wp2[k * 32 + j];
        h2[pp][j] = fmaxf(a2, 0.0f);
    }
    __syncthreads();
    if (valid && j == 0) {
        const float* hp = h2[pp];
        float lg = bp3[0];
        for (int k = 0; k < 32; k++) lg += hp[k] * Wp3[k];
        out[p] = lg;
    }
}

extern "C" void kernel_launch(void* const* d_in, const int* in_sizes, int n_in,
                              void* d_out, int out_size, void* d_ws, size_t ws_size,
                              hipStream_t stream) {
    const float* op_x      = (const float*)d_in[0];
    const float* machine_x = (const float*)d_in[1];
    const float* job_x     = (const float*)d_in[2];
    const float* W_op   = (const float*)d_in[3];
    const float* b_op   = (const float*)d_in[4];
    const float* W_mach = (const float*)d_in[5];
    const float* b_mach = (const float*)d_in[6];
    const float* W_job  = (const float*)d_in[7];
    const float* b_job  = (const float*)d_in[8];
    const float* ln_gamma = (const float*)d_in[9];
    const float* ln_beta  = (const float*)d_in[10];
    const float* Wkqv = (const float*)d_in[11];
    const float* bkqv = (const float*)d_in[12];
    const float* krel = (const float*)d_in[13];
    const float* vrel = (const float*)d_in[14];
    const float* prel = (const float*)d_in[15];
    const float* Wout = (const float*)d_in[16];
    const float* bout = (const float*)d_in[17];
    const float* skip = (const float*)d_in[18];
    const float* Wp1 = (const float*)d_in[19];
    const float* bp1 = (const float*)d_in[20];
    const float* Wp2 = (const float*)d_in[21];
    const float* bp2 = (const float*)d_in[22];
    const float* Wp3 = (const float*)d_in[23];
    const float* bp3 = (const float*)d_in[24];
    const float* Wv1 = (const float*)d_in[25];
    const float* bv1 = (const float*)d_in[26];
    const float* Wv2 = (const float*)d_in[27];
    const float* bv2 = (const float*)d_in[28];
    const int* op_idx = (const int*)d_in[37];
    const int* m_idx  = (const int*)d_in[38];

    const int NOP = in_sizes[0] / 8;
    const int NM  = in_sizes[1] / 7;
    const int NJ  = in_sizes[2] / 7;
    const int L   = in_sizes[11] / (3 * 64 * 192);
    const int P   = in_sizes[37];
    const int Ntot = NOP + NM + NJ;

    // EDGE_DEFS: (src_type, dst_type)
    const int sdef[8] = {2, 0, 0, 0, 0, 0, 1, 1};
    const int ddef[8] = {0, 2, 0, 0, 1, 1, 0, 0};
    const int toff[3] = {0, NOP, NOP + NM};
    const int* eptr[8];
    int Esz[8], eoff[9];
    eoff[0] = 0;
    for (int e = 0; e < 8; e++) {
        Esz[e] = in_sizes[29 + e] / 2;
        eptr[e] = (const int*)d_in[29 + e];
        eoff[e + 1] = eoff[e] + Esz[e];
    }
    const int Etot = eoff[8];

    // ---- workspace layout ----
    float* ws = (float*)d_ws;
    size_t o = 0;
    float* X    = ws + o; o += (size_t)Ntot * 64;
    float* KQV  = ws + o; o += (size_t)Ntot * 192;
    float* agg  = ws + o; o += (size_t)Ntot * 64;
    float* gsum = ws + o; o += 192;                 // gsum, gvec, nacc contiguous
    float* gvec = ws + o; o += 192;
    float* nacc = ws + o; o += 8;
    int* ib     = (int*)(ws + o);
    size_t io = 0;
    int* cnt    = ib + io; io += Ntot;
    int* rowptr = ib + io; io += Ntot + 1;
    int* cursor = ib + io; io += Ntot;
    int* gdst   = ib + io; io += Etot;
    int* packs  = ib + io; io += Etot;
    int* csr    = ib + io; io += Etot;

    // ---- zero: cnt + small accumulators ----
    k_zero<<<64, 256, 0, stream>>>((unsigned int*)cnt, Ntot);
    k_zero<<<1, 256, 0, stream>>>((unsigned int*)gsum, 392);

    // ---- CSR build ----
    for (int e = 0; e < 8; e++) {
        k_flat<<<(Esz[e] + 255) / 256, 256, 0, stream>>>(
            eptr[e], Esz[e], toff[sdef[e]], toff[ddef[e]], e, eoff[e], gdst, packs, cnt);
    }
    k_scan<<<1, 1024, 0, stream>>>(cnt, rowptr, cursor, Ntot, Etot);
    k_scatter<<<(Etot + 255) / 256, 256, 0, stream>>>(gdst, packs, cursor, csr, Etot);

    // ---- embed + per-type graph-norm ----
    k_embed<<<1024, 64, 0, stream>>>(op_x,      W_op,   b_op,   8, NOP, X,                           nacc + 0);
    k_embed<<<512,  64, 0, stream>>>(machine_x, W_mach, b_mach, 7, NM,  X + (size_t)NOP * 64,        nacc + 2);
    k_embed<<<512,  64, 0, stream>>>(job_x,     W_job,  b_job,  7, NJ,  X + (size_t)(NOP + NM) * 64, nacc + 4);

    k_gnorm<<<(NOP * 64 + 255) / 256, 256, 0, stream>>>(X, nacc + 0, ln_gamma, ln_beta, NOP);
    k_gnorm<<<(NM * 64 + 255) / 256, 256, 0, stream>>>(X + (size_t)NOP * 64, nacc + 2,
                                                       ln_gamma + 64, ln_beta + 64, NM);
    k_gnorm<<<(NJ * 64 + 255) / 256, 256, 0, stream>>>(X + (size_t)(NOP + NM) * 64, nacc + 4,
                                                       ln_gamma + 128, ln_beta + 128, NJ);

    // ---- HGT layers ----
    const int nb4 = (Ntot + 3) / 4;
    for (int l = 0; l < L; l++) {
        k_kqv<<<nb4, 256, 0, stream>>>(X, Wkqv, bkqv, KQV, NOP, NM, l, Ntot);
        k_attnagg<<<2048, 256, 0, stream>>>(KQV, csr, rowptr,
                                            krel + (size_t)l * 4096,
                                            vrel + (size_t)l * 4096,
                                            prel + (size_t)l * 64,
                                            agg, Ntot);
        k_out<<<nb4, 256, 0, stream>>>(agg, X, Wout, bout, skip, NOP, NM, l, Ntot);
    }

    // ---- pooling + heads ----
    dim3 pg(128, 3);
    k_pool<<<pg, 256, 0, stream>>>(X, gsum, NOP, NM, NJ);
    k_value<<<1, 192, 0, stream>>>(gsum, gvec, Wv1, bv1, Wv2, bv2,
                                   (float*)d_out + P, NOP, NM, NJ);
    HGTPolicy_53051436040798_kernel<<<(P + 3) / 4, 256, 0, stream>>>(
        X, gvec, op_idx, m_idx, Wp1, bp1, Wp2, bp2, Wp3, bp3, (float*)d_out, NOP, P);
}

// Round 7
// 921.293 us; speedup vs baseline: 1.1526x; 1.1526x over previous
//
#include <hip/hip_runtime.h>

// HGTPolicy — round 7: dispatch-count reduction (25 -> 12) + attnagg occupancy.
// All tensors float32.

// ---------------- zero fill: two regions ----------------
__global__ void k_zero2(unsigned int* a, int na, unsigned int* b, int nb) {
    int i = blockIdx.x * 256 + threadIdx.x;
    int st = gridDim.x * 256;
    int tot = na + nb;
    for (; i < tot; i += st) {
        if (i < na) a[i] = 0u; else b[i - na] = 0u;
    }
}

// ---------------- flatten all 8 edge types + dst histogram ----------------
// EDGE_DEFS src: {2,0,0,0,0,0,1,1} dst: {0,2,0,0,1,1,0,0}; offsets from NOP/NM.
__global__ void k_flat_all(const int* p0, const int* p1, const int* p2, const int* p3,
                           const int* p4, const int* p5, const int* p6, const int* p7,
                           int c1, int c2, int c3, int c4, int c5, int c6, int c7, int c8,
                           int NOP, int NM, int* gdst, int* pack, int* cnt) {
    int g = blockIdx.x * 256 + threadIdx.x;
    if (g >= c8) return;
    const int* ep; int base, E0, et, soff, doff;
    int OJ = NOP + NM;  // job offset
    if (g < c1)      { ep = p0; base = 0;  E0 = c1 - 0;  et = 0; soff = OJ;  doff = 0;  }
    else if (g < c2) { ep = p1; base = c1; E0 = c2 - c1; et = 1; soff = 0;   doff = OJ; }
    else if (g < c3) { ep = p2; base = c2; E0 = c3 - c2; et = 2; soff = 0;   doff = 0;  }
    else if (g < c4) { ep = p3; base = c3; E0 = c4 - c3; et = 3; soff = 0;   doff = 0;  }
    else if (g < c5) { ep = p4; base = c4; E0 = c5 - c4; et = 4; soff = 0;   doff = NOP;}
    else if (g < c6) { ep = p5; base = c5; E0 = c6 - c5; et = 5; soff = 0;   doff = NOP;}
    else if (g < c7) { ep = p6; base = c6; E0 = c7 - c6; et = 6; soff = NOP; doff = 0;  }
    else             { ep = p7; base = c7; E0 = c8 - c7; et = 7; soff = NOP; doff = 0;  }
    int i = g - base;
    int gd = ep[E0 + i] + doff;
    gdst[g] = gd;
    pack[g] = (ep[i] + soff) | (et << 24);
    atomicAdd(&cnt[gd], 1);
}

// ---------------- single-block parallel exclusive scan ----------------
__global__ void k_scan(const int* cnt, int* rowptr, int* cursor, int Ntot, int Etot) {
    __shared__ int s[1024];
    int t = threadIdx.x;                       // 1024 threads
    int chunk = (Ntot + 1023) >> 10;
    int lo = t * chunk;
    int hi = lo + chunk; if (hi > Ntot) hi = Ntot;
    int sum = 0;
    for (int i = lo; i < hi; i++) sum += cnt[i];
    s[t] = sum;
    __syncthreads();
    for (int off = 1; off < 1024; off <<= 1) {
        int add = (t >= off) ? s[t - off] : 0;
        __syncthreads();
        s[t] += add;
        __syncthreads();
    }
    int run = (t > 0) ? s[t - 1] : 0;
    for (int i = lo; i < hi; i++) {
        rowptr[i] = run;
        cursor[i] = run;
        run += cnt[i];
    }
    if (t == 0) rowptr[Ntot] = Etot;
}

__global__ void k_scatter(const int* gdst, const int* pack, int* cursor, int* csr, int Etot) {
    int i = blockIdx.x * 256 + threadIdx.x;
    if (i >= Etot) return;
    int d = gdst[i];
    int pos = atomicAdd(&cursor[d], 1);
    csr[pos] = pack[i];
}

// ---------------- embed ALL types + per-type moments (6 atomics/block) ----------
__global__ void k_embed_all(const float* op_x, const float* mach_x, const float* job_x,
                            const float* W_op, const float* b_op,
                            const float* W_mach, const float* b_mach,
                            const float* W_job, const float* b_job,
                            float* X, float* nacc, int N0, int N1, int N2) {
    int tid = threadIdx.x;           // 256 = 4 waves
    int j = tid & 63, w = tid >> 6;
    float w0[8], w1[7], w2[7];
    for (int k = 0; k < 8; k++) w0[k] = W_op[k * 64 + j];
    for (int k = 0; k < 7; k++) w1[k] = W_mach[k * 64 + j];
    for (int k = 0; k < 7; k++) w2[k] = W_job[k * 64 + j];
    float b0 = b_op[j], b1 = b_mach[j], b2 = b_job[j];
    float s10 = 0, s20 = 0, s11 = 0, s21 = 0, s12 = 0, s22 = 0;
    int Ntot = N0 + N1 + N2;
    for (int n = blockIdx.x * 4 + w; n < Ntot; n += gridDim.x * 4) {
        float a;
        if (n < N0) {
            const float* xr = op_x + (size_t)n * 8;
            a = b0;
            for (int k = 0; k < 8; k++) a += xr[k] * w0[k];
            s10 += a; s20 += a * a;
        } else if (n < N0 + N1) {
            const float* xr = mach_x + (size_t)(n - N0) * 7;
            a = b1;
            for (int k = 0; k < 7; k++) a += xr[k] * w1[k];
            s11 += a; s21 += a * a;
        } else {
            const float* xr = job_x + (size_t)(n - N0 - N1) * 7;
            a = b2;
            for (int k = 0; k < 7; k++) a += xr[k] * w2[k];
            s12 += a; s22 += a * a;
        }
        X[(size_t)n * 64 + j] = a;
    }
    for (int o = 32; o > 0; o >>= 1) {
        s10 += __shfl_down(s10, o); s20 += __shfl_down(s20, o);
        s11 += __shfl_down(s11, o); s21 += __shfl_down(s21, o);
        s12 += __shfl_down(s12, o); s22 += __shfl_down(s22, o);
    }
    __shared__ float r[4][6];
    if (j == 0) {
        r[w][0] = s10; r[w][1] = s20; r[w][2] = s11;
        r[w][3] = s21; r[w][4] = s12; r[w][5] = s22;
    }
    __syncthreads();
    if (tid < 6) {
        float v = r[0][tid] + r[1][tid] + r[2][tid] + r[3][tid];
        atomicAdd(&nacc[tid], v);
    }
}

// ---------------- graph-norm fused with layer-0 KQV (wave per node) ------------
__global__ void k_gkqv(float* X, const float* nacc, const float* ln_gamma,
                       const float* ln_beta, const float* Wkqv, const float* bkqv,
                       float* KQV, int N0, int N1, int N2) {
    __shared__ float xs[4][64];
    int tid = threadIdx.x;           // 256
    int w = tid >> 6, j = tid & 63;
    int Ntot = N0 + N1 + N2;
    int n = blockIdx.x * 4 + w;
    int valid = (n < Ntot);
    int t = 0;
    if (valid) {
        t = (n < N0) ? 0 : ((n < N0 + N1) ? 1 : 2);
        int Nt = (t == 0) ? N0 : ((t == 1) ? N1 : N2);
        float inv = 1.0f / ((float)Nt * 64.0f);
        float mu  = nacc[2 * t] * inv;
        float var = nacc[2 * t + 1] * inv - mu * mu;
        float sd  = sqrtf(fmaxf(var, 0.0f));
        float sc  = 1.0f / (sd + 1e-5f);
        float x = X[(size_t)n * 64 + j];
        float xn = (x - mu) * sc * ln_gamma[t * 64 + j] + ln_beta[t * 64 + j];
        X[(size_t)n * 64 + j] = xn;
        xs[w][j] = xn;
    }
    __syncthreads();
    if (!valid) return;
    const float* W = Wkqv + (size_t)t * 64 * 192;   // layer 0
    const float* b = bkqv + (size_t)t * 192;
    float a0 = b[j], a1 = b[64 + j], a2 = b[128 + j];
    const float* xw = xs[w];
    for (int k = 0; k < 64; k++) {
        float xk = xw[k];
        const float* Wk = W + k * 192;
        a0 += xk * Wk[j];
        a1 += xk * Wk[64 + j];
        a2 += xk * Wk[128 + j];
    }
    float* dst = KQV + (size_t)n * 192;
    dst[j] = a0; dst[64 + j] = a1; dst[128 + j] = a2;
}

// ---------------- fused attention + aggregation: 512 threads (8 waves) ----------
__global__ void k_attnagg(const float* KQV, const int* csr, const int* rowptr,
                          const float* krel_l, const float* vrel_l, const float* prel_l,
                          float* agg, int Ntot) {
    __shared__ float KRs[8 * 8 * 72];   // stride 72 -> 2-way bank alias only (free)
    __shared__ float VRs[8 * 8 * 72];
    __shared__ float PRs[64];
    int tid = threadIdx.x;   // 512
    for (int i = tid; i < 4096; i += 512) {
        int eth = i >> 6, rest = i & 63;
        KRs[eth * 72 + rest] = krel_l[i];
        VRs[eth * 72 + rest] = vrel_l[i];
    }
    if (tid < 64) PRs[tid] = prel_l[tid];
    __syncthreads();

    int j = tid & 63, h = j >> 3, ee = j & 7;
    int wave  = blockIdx.x * 8 + (tid >> 6);
    int nwave = gridDim.x * 8;
    for (int n = wave; n < Ntot; n += nwave) {
        float qv = KQV[(size_t)n * 192 + 64 + j];
        float num = 0.0f, den = 0.0f;
        int e0 = rowptr[n], e1 = rowptr[n + 1];
        for (int idx = e0; idx < e1; idx++) {
            int pk = csr[idx];
            int sn = pk & 0xFFFFFF;
            int et = ((unsigned int)pk) >> 24;
            const float* kr = KQV + (size_t)sn * 192 + h * 8;
            const float* vr = kr + 128;
            const float* KR = KRs + (et * 8 + h) * 72;
            const float* VR = VRs + (et * 8 + h) * 72;
            float ke = 0.0f, ve = 0.0f;
#pragma unroll
            for (int d = 0; d < 8; d++) {
                float kd = kr[d], vd = vr[d];
                ke += kd * KR[d * 8 + ee];
                ve += vd * VR[d * 8 + ee];
            }
            float t = qv * ke;
            t += __shfl_xor(t, 1);
            t += __shfl_xor(t, 2);
            t += __shfl_xor(t, 4);
            float ex = expf(t * PRs[et * 8 + h] * 0.35355339059327373f);
            num += ex * ve;
            den += ex;
        }
        agg[(size_t)n * 64 + j] = (den > 0.0f) ? (num / den) : 0.0f;
    }
}

// ---- output projection + skip gate, optionally fused with next-layer KQV -------
__global__ void k_outkqv(const float* agg, float* X, const float* Wout_l,
                         const float* bout_l, const float* skip_l,
                         const float* Wkqv_n, const float* bkqv_n, float* KQV,
                         int N0, int N1, int Ntot, int do_kqv) {
    __shared__ float ga[4][64];
    __shared__ float xs[4][64];
    int tid = threadIdx.x;           // 256
    int w = tid >> 6, j = tid & 63;
    int n = blockIdx.x * 4 + w;
    int valid = (n < Ntot);
    int t = 0;
    float xold = 0.0f;
    if (valid) {
        t = (n < N0) ? 0 : ((n < N0 + N1) ? 1 : 2);
        float x = agg[(size_t)n * 64 + j];
        ga[w][j] = 0.5f * x * (1.0f + erff(x * 0.70710678118654752f));  // exact gelu
        xold = X[(size_t)n * 64 + j];
    }
    __syncthreads();
    if (valid) {
        const float* W = Wout_l + (size_t)t * 64 * 64;
        const float* b = bout_l + (size_t)t * 64;
        const float* gw = ga[w];
        float o = b[j];
        for (int k = 0; k < 64; k++) o += gw[k] * W[k * 64 + j];
        float gk = 1.0f / (1.0f + expf(-skip_l[t]));
        float xn = gk * o + (1.0f - gk) * xold;
        X[(size_t)n * 64 + j] = xn;
        xs[w][j] = xn;
    }
    __syncthreads();
    if (!valid || !do_kqv) return;
    const float* W = Wkqv_n + (size_t)t * 64 * 192;
    const float* b = bkqv_n + (size_t)t * 192;
    float a0 = b[j], a1 = b[64 + j], a2 = b[128 + j];
    const float* xw = xs[w];
    for (int k = 0; k < 64; k++) {
        float xk = xw[k];
        const float* Wk = W + k * 192;
        a0 += xk * Wk[j];
        a1 += xk * Wk[64 + j];
        a2 += xk * Wk[128 + j];
    }
    float* dst = KQV + (size_t)n * 192;
    dst[j] = a0; dst[64 + j] = a1; dst[128 + j] = a2;
}

// ---------------- global mean pooling (wide) ----------------
__global__ void k_pool(const float* X, float* gsum, int N0, int N1, int N2) {
    __shared__ float red[256];
    int t = blockIdx.y;
    int tid = threadIdx.x;
    int j = tid & 63, w = tid >> 6;
    int N   = (t == 0) ? N0 : ((t == 1) ? N1 : N2);
    int off = (t == 0) ? 0  : ((t == 1) ? N0 : N0 + N1);
    const float* base = X + (size_t)off * 64;
    float s = 0.0f;
    for (int r = blockIdx.x * 4 + w; r < N; r += gridDim.x * 4)
        s += base[(size_t)r * 64 + j];
    red[tid] = s;
    __syncthreads();
    if (tid < 64) {
        float tot = red[j] + red[64 + j] + red[128 + j] + red[192 + j];
        atomicAdd(&gsum[t * 64 + j], tot);
    }
}

// ---------------- policy head (4 pairs/block) + value head (last block) ---------
__global__ void HGTPolicy_53051436040798_kernel(
        const float* X, const float* gsum, const int* op_idx, const int* m_idx,
        const float* Wp1, const float* bp1, const float* Wp2, const float* bp2,
        const float* Wp3, const float* bp3,
        const float* Wv1, const float* bv1, const float* Wv2, const float* bv2,
        float* out, int N0, int N1, int N2, int P, int nb) {
    int tid = threadIdx.x;           // 256
    if (blockIdx.x == nb) {
        // ---- value head ----
        __shared__ float g[192];
        __shared__ float h1[64];
        int j = tid;
        if (j < 192) {
            float Nd = (j < 64) ? (float)N0 : ((j < 128) ? (float)N1 : (float)N2);
            g[j] = gsum[j] / Nd;
        }
        __syncthreads();
        if (j < 64) {
            float a = bv1[j];
            for (int k = 0; k < 192; k++) a += g[k] * Wv1[k * 64 + j];
            h1[j] = fmaxf(a, 0.0f);
        }
        __syncthreads();
        if (j == 0) {
            float v = bv2[0];
            for (int k = 0; k < 64; k++) v += h1[k] * Wv2[k];
            out[P] = v;
        }
        return;
    }
    // ---- policy ----
    __shared__ float z[4][320];
    __shared__ float h1p[4][64];
    __shared__ float h2p[4][32];
    int pp = tid >> 6, j = tid & 63;
    int p = blockIdx.x * 4 + pp;
    int valid = (p < P);
    if (valid) {
        int on = op_idx[p], mn = m_idx[p];
        z[pp][j]       = X[(size_t)on * 64 + j];
        z[pp][64 + j]  = X[(size_t)(N0 + mn) * 64 + j];
        z[pp][128 + j] = gsum[j] / (float)N0;
        z[pp][192 + j] = gsum[64 + j] / (float)N1;
        z[pp][256 + j] = gsum[128 + j] / (float)N2;
    }
    __syncthreads();
    if (valid) {
        const float* zp = z[pp];
        float a = bp1[j];
        for (int k = 0; k < 320; k++) a += zp[k] * Wp1[k * 64 + j];
        h1p[pp][j] = fmaxf(a, 0.0f);
    }
    __syncthreads();
    if (valid && j < 32) {
        const float* hp = h1p[pp];
        float a2 = bp2[j];
        for (int k = 0; k < 64; k++) a2 += hp[k] * Wp2[k * 32 + j];
        h2p[pp][j] = fmaxf(a2, 0.0f);
    }
    __syncthreads();
    if (valid && j == 0) {
        const float* hp = h2p[pp];
        float lg = bp3[0];
        for (int k = 0; k < 32; k++) lg += hp[k] * Wp3[k];
        out[p] = lg;
    }
}

extern "C" void kernel_launch(void* const* d_in, const int* in_sizes, int n_in,
                              void* d_out, int out_size, void* d_ws, size_t ws_size,
                              hipStream_t stream) {
    const float* op_x      = (const float*)d_in[0];
    const float* machine_x = (const float*)d_in[1];
    const float* job_x     = (const float*)d_in[2];
    const float* W_op   = (const float*)d_in[3];
    const float* b_op   = (const float*)d_in[4];
    const float* W_mach = (const float*)d_in[5];
    const float* b_mach = (const float*)d_in[6];
    const float* W_job  = (const float*)d_in[7];
    const float* b_job  = (const float*)d_in[8];
    const float* ln_gamma = (const float*)d_in[9];
    const float* ln_beta  = (const float*)d_in[10];
    const float* Wkqv = (const float*)d_in[11];
    const float* bkqv = (const float*)d_in[12];
    const float* krel = (const float*)d_in[13];
    const float* vrel = (const float*)d_in[14];
    const float* prel = (const float*)d_in[15];
    const float* Wout = (const float*)d_in[16];
    const float* bout = (const float*)d_in[17];
    const float* skip = (const float*)d_in[18];
    const float* Wp1 = (const float*)d_in[19];
    const float* bp1 = (const float*)d_in[20];
    const float* Wp2 = (const float*)d_in[21];
    const float* bp2 = (const float*)d_in[22];
    const float* Wp3 = (const float*)d_in[23];
    const float* bp3 = (const float*)d_in[24];
    const float* Wv1 = (const float*)d_in[25];
    const float* bv1 = (const float*)d_in[26];
    const float* Wv2 = (const float*)d_in[27];
    const float* bv2 = (const float*)d_in[28];
    const int* op_idx = (const int*)d_in[37];
    const int* m_idx  = (const int*)d_in[38];

    const int NOP = in_sizes[0] / 8;
    const int NM  = in_sizes[1] / 7;
    const int NJ  = in_sizes[2] / 7;
    const int L   = in_sizes[11] / (3 * 64 * 192);
    const int P   = in_sizes[37];
    const int Ntot = NOP + NM + NJ;

    const int* eptr[8];
    int eoff[9];
    eoff[0] = 0;
    for (int e = 0; e < 8; e++) {
        eptr[e] = (const int*)d_in[29 + e];
        eoff[e + 1] = eoff[e] + in_sizes[29 + e] / 2;
    }
    const int Etot = eoff[8];

    // ---- workspace layout ----
    float* ws = (float*)d_ws;
    size_t o = 0;
    float* X    = ws + o; o += (size_t)Ntot * 64;
    float* KQV  = ws + o; o += (size_t)Ntot * 192;
    float* agg  = ws + o; o += (size_t)Ntot * 64;
    float* gsum = ws + o; o += 192;                 // gsum + nacc contiguous (zeroed)
    float* nacc = ws + o; o += 8;
    int* ib     = (int*)(ws + o);
    size_t io = 0;
    int* cnt    = ib + io; io += Ntot;
    int* rowptr = ib + io; io += Ntot + 1;
    int* cursor = ib + io; io += Ntot;
    int* gdst   = ib + io; io += Etot;
    int* packs  = ib + io; io += Etot;
    int* csr    = ib + io; io += Etot;

    // 1) zero cnt + (gsum,nacc)
    k_zero2<<<64, 256, 0, stream>>>((unsigned int*)cnt, Ntot, (unsigned int*)gsum, 200);

    // 2-4) CSR build
    k_flat_all<<<(Etot + 255) / 256, 256, 0, stream>>>(
        eptr[0], eptr[1], eptr[2], eptr[3], eptr[4], eptr[5], eptr[6], eptr[7],
        eoff[1], eoff[2], eoff[3], eoff[4], eoff[5], eoff[6], eoff[7], eoff[8],
        NOP, NM, gdst, packs, cnt);
    k_scan<<<1, 1024, 0, stream>>>(cnt, rowptr, cursor, Ntot, Etot);
    k_scatter<<<(Etot + 255) / 256, 256, 0, stream>>>(gdst, packs, cursor, csr, Etot);

    // 5) embed all types
    k_embed_all<<<512, 256, 0, stream>>>(op_x, machine_x, job_x,
                                         W_op, b_op, W_mach, b_mach, W_job, b_job,
                                         X, nacc, NOP, NM, NJ);

    // 6) graph-norm + layer-0 KQV
    const int nb4 = (Ntot + 3) / 4;
    k_gkqv<<<nb4, 256, 0, stream>>>(X, nacc, ln_gamma, ln_beta, Wkqv, bkqv, KQV,
                                    NOP, NM, NJ);

    // 7..10) layers: attnagg + (out fused with next kqv)
    for (int l = 0; l < L; l++) {
        k_attnagg<<<1024, 512, 0, stream>>>(KQV, csr, rowptr,
                                            krel + (size_t)l * 4096,
                                            vrel + (size_t)l * 4096,
                                            prel + (size_t)l * 64,
                                            agg, Ntot);
        int do_kqv = (l + 1 < L);
        const float* Wkqv_n = Wkqv + (size_t)(do_kqv ? (l + 1) : 0) * 3 * 64 * 192;
        const float* bkqv_n = bkqv + (size_t)(do_kqv ? (l + 1) : 0) * 3 * 192;
        k_outkqv<<<nb4, 256, 0, stream>>>(agg, X,
                                          Wout + (size_t)l * 3 * 64 * 64,
                                          bout + (size_t)l * 3 * 64,
                                          skip + (size_t)l * 3,
                                          Wkqv_n, bkqv_n, KQV,
                                          NOP, NM, Ntot, do_kqv);
    }

    // 11) pooling
    dim3 pg(128, 3);
    k_pool<<<pg, 256, 0, stream>>>(X, gsum, NOP, NM, NJ);

    // 12) policy + value
    const int nbP = (P + 3) / 4;
    HGTPolicy_53051436040798_kernel<<<nbP + 1, 256, 0, stream>>>(
        X, gsum, op_idx, m_idx, Wp1, bp1, Wp2, bp2, Wp3, bp3,
        Wv1, bv1, Wv2, bv2, (float*)d_out, NOP, NM, NJ, P, nbP);
}